// Round 1
// baseline (143.677 us; speedup 1.0000x reference)
//
#include <hip/hip_runtime.h>

#define TWO_N 8192
#define HALF_N 4096
#define DIM 256

#define ROWS_PER_WAVE 32
#define ROWS_PER_BLOCK 128
#define ROWBLOCKS (TWO_N / ROWS_PER_BLOCK)   // 64
#define COLSPLIT 16
#define COLS_PER_BLOCK (TWO_N / COLSPLIT)    // 512

typedef __attribute__((ext_vector_type(8))) short bf16x8;
typedef __attribute__((ext_vector_type(4))) float f32x4;

__device__ __forceinline__ float bf2f(unsigned short u) {
  return __uint_as_float(((unsigned int)u) << 16);
}
__device__ __forceinline__ unsigned short f2bf(float f) {
  unsigned int u = __float_as_uint(f);
  return (unsigned short)((u + 0x7FFFu + ((u >> 16) & 1u)) >> 16);
}

// K1: L2-normalize each row of [z_i; z_j], store as bf16; also zero rowsum.
__global__ __launch_bounds__(256) void k_norm(const float* __restrict__ zi,
                                              const float* __restrict__ zj,
                                              unsigned short* __restrict__ rn,
                                              float* __restrict__ rowsum) {
  int wave = threadIdx.x >> 6, lane = threadIdx.x & 63;
  int row = blockIdx.x * 4 + wave;
  if (threadIdx.x < 4) rowsum[blockIdx.x * 4 + threadIdx.x] = 0.0f;
  const float* src = (row < HALF_N) ? (zi + (size_t)row * DIM)
                                    : (zj + (size_t)(row - HALF_N) * DIM);
  float4 v = *reinterpret_cast<const float4*>(src + lane * 4);
  float ss = v.x * v.x + v.y * v.y + v.z * v.z + v.w * v.w;
  #pragma unroll
  for (int m = 32; m >= 1; m >>= 1) ss += __shfl_xor(ss, m, 64);
  float r = rsqrtf(ss);
  ushort4 o;
  o.x = f2bf(v.x * r); o.y = f2bf(v.y * r);
  o.z = f2bf(v.z * r); o.w = f2bf(v.w * r);
  *reinterpret_cast<ushort4*>(rn + (size_t)row * DIM + lane * 4) = o;
}

// K2: Gram matrix tile-by-tile via MFMA; streaming sum of exp(sim-10) per row.
// sim[i][j] = dot(rn_i, rn_j)/0.1 ; exp(sim-10) = exp2(14.42695*(dot-1)).
// C-fragment layout (16x16x32): col = lane&15, row = (lane>>4)*4 + reg.
__global__ __launch_bounds__(256) void k_sim(const unsigned short* __restrict__ rn,
                                             float* __restrict__ rowsum) {
  int rb = blockIdx.x & (ROWBLOCKS - 1);
  int cs = blockIdx.x >> 6;                 // / ROWBLOCKS
  int wave = threadIdx.x >> 6, lane = threadIdx.x & 63;
  int lrow = lane & 15, kgrp = lane >> 4;
  int r0 = rb * ROWS_PER_BLOCK + wave * ROWS_PER_WAVE;

  // A fragments for two 16-row strips (rows fixed for whole block lifetime)
  bf16x8 a0[8], a1[8];
  {
    const unsigned short* p0 = rn + (size_t)(r0 + lrow) * DIM + kgrp * 8;
    const unsigned short* p1 = p0 + 16 * DIM;
    #pragma unroll
    for (int kk = 0; kk < 8; ++kk) {
      a0[kk] = *reinterpret_cast<const bf16x8*>(p0 + kk * 32);
      a1[kk] = *reinterpret_cast<const bf16x8*>(p1 + kk * 32);
    }
  }

  float se0[4] = {0.f, 0.f, 0.f, 0.f}, se1[4] = {0.f, 0.f, 0.f, 0.f};
  const int cbase = cs * COLS_PER_BLOCK;
  for (int c0 = cbase; c0 < cbase + COLS_PER_BLOCK; c0 += 16) {
    const unsigned short* bp = rn + (size_t)(c0 + lrow) * DIM + kgrp * 8;
    f32x4 acc0 = {0.f, 0.f, 0.f, 0.f}, acc1 = {0.f, 0.f, 0.f, 0.f};
    #pragma unroll
    for (int kk = 0; kk < 8; ++kk) {
      bf16x8 b = *reinterpret_cast<const bf16x8*>(bp + kk * 32);
      acc0 = __builtin_amdgcn_mfma_f32_16x16x32_bf16(a0[kk], b, acc0, 0, 0, 0);
      acc1 = __builtin_amdgcn_mfma_f32_16x16x32_bf16(a1[kk], b, acc1, 0, 0, 0);
    }
    bool d0 = (c0 == r0), d1 = (c0 == r0 + 16);
    #pragma unroll
    for (int g = 0; g < 4; ++g) {
      float e0 = __builtin_amdgcn_exp2f(fmaf(acc0[g], 14.4269504089f, -14.4269504089f));
      float e1 = __builtin_amdgcn_exp2f(fmaf(acc1[g], 14.4269504089f, -14.4269504089f));
      if (d0 && (lrow == kgrp * 4 + g)) e0 = 0.0f;   // mask diagonal
      if (d1 && (lrow == kgrp * 4 + g)) e1 = 0.0f;
      se0[g] += e0;
      se1[g] += e1;
    }
  }

  // reduce the 16 column-lanes (low 4 bits of lane id), then one atomic per row
  #pragma unroll
  for (int g = 0; g < 4; ++g) {
    float s0 = se0[g], s1 = se1[g];
    #pragma unroll
    for (int m = 1; m <= 8; m <<= 1) {
      s0 += __shfl_xor(s0, m, 64);
      s1 += __shfl_xor(s1, m, 64);
    }
    if (lrow == 0) {
      atomicAdd(&rowsum[r0 + kgrp * 4 + g], s0);
      atomicAdd(&rowsum[r0 + 16 + kgrp * 4 + g], s1);
    }
  }
}

// K3: per-row  lse - pos.  lse = 10 + ln(rowsum); pos = 10*dot(rn_i, rn_j).
__global__ __launch_bounds__(256) void k_row(const unsigned short* __restrict__ rn,
                                             const float* __restrict__ rowsum,
                                             float* __restrict__ vals) {
  int wave = threadIdx.x >> 6, lane = threadIdx.x & 63;
  int i = blockIdx.x * 4 + wave;
  int j = (i + HALF_N) & (TWO_N - 1);
  ushort4 a = *reinterpret_cast<const ushort4*>(rn + (size_t)i * DIM + lane * 4);
  ushort4 b = *reinterpret_cast<const ushort4*>(rn + (size_t)j * DIM + lane * 4);
  float dot = bf2f(a.x) * bf2f(b.x) + bf2f(a.y) * bf2f(b.y) +
              bf2f(a.z) * bf2f(b.z) + bf2f(a.w) * bf2f(b.w);
  #pragma unroll
  for (int m = 32; m >= 1; m >>= 1) dot += __shfl_xor(dot, m, 64);
  if (lane == 0) {
    float pos = dot * 10.0f;
    float lse = 10.0f + 0.69314718056f * __builtin_amdgcn_logf(rowsum[i]);
    vals[i] = lse - pos;
  }
}

// K4: deterministic single-block mean of 8192 values.
__global__ __launch_bounds__(256) void k_reduce(const float* __restrict__ vals,
                                               float* __restrict__ out) {
  __shared__ float ls[4];
  int lane = threadIdx.x & 63, wave = threadIdx.x >> 6;
  float s = 0.0f;
  for (int i = threadIdx.x; i < TWO_N; i += 256) s += vals[i];
  #pragma unroll
  for (int m = 32; m >= 1; m >>= 1) s += __shfl_xor(s, m, 64);
  if (lane == 0) ls[wave] = s;
  __syncthreads();
  if (threadIdx.x == 0)
    out[0] = (ls[0] + ls[1] + ls[2] + ls[3]) * (1.0f / TWO_N);
}

extern "C" void kernel_launch(void* const* d_in, const int* in_sizes, int n_in,
                              void* d_out, int out_size, void* d_ws, size_t ws_size,
                              hipStream_t stream) {
  const float* zi = (const float*)d_in[0];
  const float* zj = (const float*)d_in[1];
  unsigned short* rn = (unsigned short*)d_ws;                      // 4 MB bf16
  float* rowsum = (float*)((char*)d_ws + (size_t)TWO_N * DIM * 2); // 32 KB
  float* vals = rowsum + TWO_N;                                    // 32 KB
  float* out = (float*)d_out;

  hipLaunchKernelGGL(k_norm, dim3(TWO_N / 4), dim3(256), 0, stream, zi, zj, rn, rowsum);
  hipLaunchKernelGGL(k_sim, dim3(ROWBLOCKS * COLSPLIT), dim3(256), 0, stream, rn, rowsum);
  hipLaunchKernelGGL(k_row, dim3(TWO_N / 4), dim3(256), 0, stream, rn, rowsum, vals);
  hipLaunchKernelGGL(k_reduce, dim3(1), dim3(256), 0, stream, vals, out);
}

// Round 2
// 53.088 us; speedup vs baseline: 2.7064x; 2.7064x over previous
//
#include <hip/hip_runtime.h>

#define TWO_N 8192
#define HALF_N 4096
#define DIM 256

#define ROWS_PER_WAVE 32
#define ROWS_PER_BLOCK 128
#define ROWBLOCKS (TWO_N / ROWS_PER_BLOCK)   // 64
#define COLSPLIT 16
#define COLS_PER_BLOCK (TWO_N / COLSPLIT)    // 512
#define CH_COLS 32
#define CHUNK_BYTES (CH_COLS * DIM * 2)      // 16 KB
#define NCHUNK (COLS_PER_BLOCK / CH_COLS)    // 16

typedef __attribute__((ext_vector_type(8))) short bf16x8;
typedef __attribute__((ext_vector_type(4))) float f32x4;

__device__ __forceinline__ float bf2f(unsigned short u) {
  return __uint_as_float(((unsigned int)u) << 16);
}
__device__ __forceinline__ unsigned short f2bf(float f) {
  unsigned int u = __float_as_uint(f);
  return (unsigned short)((u + 0x7FFFu + ((u >> 16) & 1u)) >> 16);
}
__device__ __forceinline__ void async_copy16(void* lds_dst, const void* g_src) {
  __builtin_amdgcn_global_load_lds(
      (const __attribute__((address_space(1))) unsigned int*)g_src,
      (__attribute__((address_space(3))) unsigned int*)lds_dst, 16, 0, 0);
}

// K1: L2-normalize each row of [z_i; z_j], store as bf16; also zero rowsum.
__global__ __launch_bounds__(256) void k_norm(const float* __restrict__ zi,
                                              const float* __restrict__ zj,
                                              unsigned short* __restrict__ rn,
                                              float* __restrict__ rowsum) {
  int wave = threadIdx.x >> 6, lane = threadIdx.x & 63;
  int row = blockIdx.x * 4 + wave;
  if (threadIdx.x < 4) rowsum[blockIdx.x * 4 + threadIdx.x] = 0.0f;
  const float* src = (row < HALF_N) ? (zi + (size_t)row * DIM)
                                    : (zj + (size_t)(row - HALF_N) * DIM);
  float4 v = *reinterpret_cast<const float4*>(src + lane * 4);
  float ss = v.x * v.x + v.y * v.y + v.z * v.z + v.w * v.w;
  #pragma unroll
  for (int m = 32; m >= 1; m >>= 1) ss += __shfl_xor(ss, m, 64);
  float r = rsqrtf(ss);
  ushort4 o;
  o.x = f2bf(v.x * r); o.y = f2bf(v.y * r);
  o.z = f2bf(v.z * r); o.w = f2bf(v.w * r);
  *reinterpret_cast<ushort4*>(rn + (size_t)row * DIM + lane * 4) = o;
}

// K2: Gram matrix via MFMA with LDS-staged B panels (double-buffered,
// bank-swizzled), streaming sum of exp(sim-10) per row.
// C-fragment (16x16x32): col = lane&15, row = (lane>>4)*4 + reg.
__global__ __launch_bounds__(256, 4) void k_sim(const unsigned short* __restrict__ rn,
                                                float* __restrict__ rowsum) {
  __shared__ alignas(16) char lds[2][CHUNK_BYTES];
  int cs = blockIdx.x & (COLSPLIT - 1);       // low bits -> XCD affinity
  int rb = blockIdx.x >> 4;
  int wave = threadIdx.x >> 6, lane = threadIdx.x & 63;
  int lrow = lane & 15, kgrp = lane >> 4;
  int r0 = rb * ROWS_PER_BLOCK + wave * ROWS_PER_WAVE;
  const int cbase = cs * COLS_PER_BLOCK;

  // A fragments: two 16-row strips, resident in VGPRs for the whole kernel.
  bf16x8 a0[8], a1[8];
  {
    const unsigned short* p0 = rn + (size_t)(r0 + lrow) * DIM + kgrp * 8;
    const unsigned short* p1 = p0 + 16 * DIM;
    #pragma unroll
    for (int kk = 0; kk < 8; ++kk) {
      a0[kk] = *reinterpret_cast<const bf16x8*>(p0 + kk * 32);
      a1[kk] = *reinterpret_cast<const bf16x8*>(p1 + kk * 32);
    }
  }

  float se0[4] = {0.f, 0.f, 0.f, 0.f}, se1[4] = {0.f, 0.f, 0.f, 0.f};

  // Stage one 32-col chunk (16 KB) into lds[buf]; source pre-swizzled so the
  // swizzled ds_read below is conflict-minimal (linear LDS dest, rule #21).
  auto stage = [&](int buf, int ch) {
    const char* gb = (const char*)rn + (size_t)(cbase + ch * CH_COLS) * (DIM * 2);
    #pragma unroll
    for (int t = 0; t < 4; ++t) {
      int r = wave * 4 + t;                  // 1 KB region = 2 columns
      int col = 2 * r + (lane >> 5);
      int j = (lane & 31) ^ (col & 7);
      async_copy16(&lds[buf][r * 1024], gb + col * 512 + j * 16);
    }
  };

  stage(0, 0);
  __syncthreads();

  for (int ch = 0; ch < NCHUNK; ++ch) {
    if (ch + 1 < NCHUNK) stage((ch + 1) & 1, ch + 1);
    int buf = ch & 1;
    #pragma unroll
    for (int half = 0; half < 2; ++half) {
      int cc = half * 16;
      int c0g = cbase + ch * CH_COLS + cc;
      int col_local = cc + lrow;
      const char* bp = &lds[buf][col_local * 512];
      int cx = col_local & 7;
      f32x4 acc0 = {0.f, 0.f, 0.f, 0.f}, acc1 = {0.f, 0.f, 0.f, 0.f};
      #pragma unroll
      for (int kk = 0; kk < 8; ++kk) {
        int j = (kgrp + 4 * kk) ^ cx;        // swizzled chunk index
        bf16x8 b = *reinterpret_cast<const bf16x8*>(bp + j * 16);
        acc0 = __builtin_amdgcn_mfma_f32_16x16x32_bf16(a0[kk], b, acc0, 0, 0, 0);
        acc1 = __builtin_amdgcn_mfma_f32_16x16x32_bf16(a1[kk], b, acc1, 0, 0, 0);
      }
      bool d0 = (c0g == r0), d1 = (c0g == r0 + 16);
      #pragma unroll
      for (int g = 0; g < 4; ++g) {
        float e0 = __builtin_amdgcn_exp2f(fmaf(acc0[g], 14.4269504089f, -14.4269504089f));
        float e1 = __builtin_amdgcn_exp2f(fmaf(acc1[g], 14.4269504089f, -14.4269504089f));
        if (d0 && (lrow == kgrp * 4 + g)) e0 = 0.0f;   // mask diagonal
        if (d1 && (lrow == kgrp * 4 + g)) e1 = 0.0f;
        se0[g] += e0;
        se1[g] += e1;
      }
    }
    __syncthreads();   // drains vmcnt (next-chunk stage) + lgkm, barrier
  }

  // reduce the 16 column-lanes, then one atomic per row
  #pragma unroll
  for (int g = 0; g < 4; ++g) {
    float s0 = se0[g], s1 = se1[g];
    #pragma unroll
    for (int m = 1; m <= 8; m <<= 1) {
      s0 += __shfl_xor(s0, m, 64);
      s1 += __shfl_xor(s1, m, 64);
    }
    if (lrow == 0) {
      atomicAdd(&rowsum[r0 + kgrp * 4 + g], s0);
      atomicAdd(&rowsum[r0 + 16 + kgrp * 4 + g], s1);
    }
  }
}

// K3: per-row  lse - pos.  lse = 10 + ln(rowsum); pos = 10*dot(rn_i, rn_j).
__global__ __launch_bounds__(256) void k_row(const unsigned short* __restrict__ rn,
                                             const float* __restrict__ rowsum,
                                             float* __restrict__ vals) {
  int wave = threadIdx.x >> 6, lane = threadIdx.x & 63;
  int i = blockIdx.x * 4 + wave;
  int j = (i + HALF_N) & (TWO_N - 1);
  ushort4 a = *reinterpret_cast<const ushort4*>(rn + (size_t)i * DIM + lane * 4);
  ushort4 b = *reinterpret_cast<const ushort4*>(rn + (size_t)j * DIM + lane * 4);
  float dot = bf2f(a.x) * bf2f(b.x) + bf2f(a.y) * bf2f(b.y) +
              bf2f(a.z) * bf2f(b.z) + bf2f(a.w) * bf2f(b.w);
  #pragma unroll
  for (int m = 32; m >= 1; m >>= 1) dot += __shfl_xor(dot, m, 64);
  if (lane == 0) {
    float pos = dot * 10.0f;
    float lse = 10.0f + 0.69314718056f * __builtin_amdgcn_logf(rowsum[i]);
    vals[i] = lse - pos;
  }
}

// K4: deterministic single-block mean of 8192 values.
__global__ __launch_bounds__(1024) void k_reduce(const float* __restrict__ vals,
                                                float* __restrict__ out) {
  __shared__ float ls[16];
  int lane = threadIdx.x & 63, wave = threadIdx.x >> 6;
  float s = 0.0f;
  for (int i = threadIdx.x; i < TWO_N; i += 1024) s += vals[i];
  #pragma unroll
  for (int m = 32; m >= 1; m >>= 1) s += __shfl_xor(s, m, 64);
  if (lane == 0) ls[wave] = s;
  __syncthreads();
  if (threadIdx.x == 0) {
    float t = 0.0f;
    #pragma unroll
    for (int w = 0; w < 16; ++w) t += ls[w];
    out[0] = t * (1.0f / TWO_N);
  }
}

extern "C" void kernel_launch(void* const* d_in, const int* in_sizes, int n_in,
                              void* d_out, int out_size, void* d_ws, size_t ws_size,
                              hipStream_t stream) {
  const float* zi = (const float*)d_in[0];
  const float* zj = (const float*)d_in[1];
  unsigned short* rn = (unsigned short*)d_ws;                      // 4 MB bf16
  float* rowsum = (float*)((char*)d_ws + (size_t)TWO_N * DIM * 2); // 32 KB
  float* vals = rowsum + TWO_N;                                    // 32 KB
  float* out = (float*)d_out;

  hipLaunchKernelGGL(k_norm, dim3(TWO_N / 4), dim3(256), 0, stream, zi, zj, rn, rowsum);
  hipLaunchKernelGGL(k_sim, dim3(ROWBLOCKS * COLSPLIT), dim3(256), 0, stream, rn, rowsum);
  hipLaunchKernelGGL(k_row, dim3(TWO_N / 4), dim3(256), 0, stream, rn, rowsum, vals);
  hipLaunchKernelGGL(k_reduce, dim3(1), dim3(1024), 0, stream, vals, out);
}